// Round 5
// baseline (1051.124 us; speedup 1.0000x reference)
//
#include <hip/hip_runtime.h>
#include <hip/hip_bf16.h>

// Problem constants
#define NN 50000
#define EE 800000
#define DD 128
#define FF 16
#define LL 5
#define NB 782            // ceil(50000/64) row-tile blocks in GEMMs
#define NPART (NB * 4)    // per (block, wave) BN partials = 3128

typedef __attribute__((ext_vector_type(8))) short bf16x8;
typedef __attribute__((ext_vector_type(4))) float f32x4;

__device__ __forceinline__ unsigned short f2bf(float f) {
    union { float f; unsigned int u; } v; v.f = f;
    unsigned int u = v.u;
    unsigned int r = (u + 0x7fffu + ((u >> 16) & 1u)) >> 16;
    return (unsigned short)r;
}
__device__ __forceinline__ float bf2f(unsigned short s) {
    union { unsigned int u; float f; } v; v.u = ((unsigned int)s) << 16;
    return v.f;
}
#define BFLO(u) __uint_as_float((unsigned int)(u) << 16)
#define BFHI(u) __uint_as_float((unsigned int)(u) & 0xffff0000u)

// ---------------- node encoder: h = x @ W_node + b_node (+ bf16 mirror) ----------------
__global__ void k_node_enc(const float* __restrict__ x, const float* __restrict__ Wn,
                           const float* __restrict__ bn, float* __restrict__ h,
                           unsigned short* __restrict__ h_bf)
{
    const int t = blockIdx.x * 256 + threadIdx.x;   // grid exactly N*128
    const int i = t >> 7, d = t & 127;
    const float4* x4 = (const float4*)(x + (size_t)i * 16);
    float4 a0 = x4[0], a1 = x4[1], a2 = x4[2], a3 = x4[3];
    float acc = bn[d];
    acc += a0.x*Wn[0*128+d] + a0.y*Wn[1*128+d] + a0.z*Wn[2*128+d] + a0.w*Wn[3*128+d];
    acc += a1.x*Wn[4*128+d] + a1.y*Wn[5*128+d] + a1.z*Wn[6*128+d] + a1.w*Wn[7*128+d];
    acc += a2.x*Wn[8*128+d] + a2.y*Wn[9*128+d] + a2.z*Wn[10*128+d] + a2.w*Wn[11*128+d];
    acc += a3.x*Wn[12*128+d] + a3.y*Wn[13*128+d] + a3.z*Wn[14*128+d] + a3.w*Wn[15*128+d];
    h[t] = acc;
    h_bf[t] = f2bf(acc);
}

// ---------------- CSR build ----------------
__global__ void k_count(const int* __restrict__ ei, int* __restrict__ counts)
{
    const int e = blockIdx.x * 256 + threadIdx.x;   // grid exactly E
    atomicAdd(&counts[ei[EE + e]], 1);
}

__global__ __launch_bounds__(1024) void k_scan(int* __restrict__ counts, int* __restrict__ row_ptr)
{
    __shared__ int wsum[16];
    __shared__ int carry;
    const int tid = threadIdx.x, lane = tid & 63, w = tid >> 6;
    if (tid == 0) carry = 0;
    __syncthreads();
    for (int base = 0; base < NN; base += 1024) {
        const int i = base + tid;
        const int v = (i < NN) ? counts[i] : 0;
        int x = v;
        #pragma unroll
        for (int off = 1; off < 64; off <<= 1) {
            const int t = __shfl_up(x, off);
            if (lane >= off) x += t;
        }
        if (lane == 63) wsum[w] = x;
        __syncthreads();
        int woff = 0, total = 0;
        #pragma unroll
        for (int j = 0; j < 16; ++j) { const int s = wsum[j]; total += s; if (j < w) woff += s; }
        const int ex = carry + woff + x - v;
        if (i < NN) { row_ptr[i] = ex; counts[i] = ex; }
        __syncthreads();
        if (tid == 0) carry += total;
        __syncthreads();
    }
    if (tid == 0) row_ptr[NN] = carry;
}

// Fill CSR slots AND permute+convert edge features to bf16 in CSR order.
__global__ void k_fill(const int* __restrict__ ei, const float* __restrict__ ea,
                       int* __restrict__ cursor, int* __restrict__ src_perm,
                       unsigned short* __restrict__ ea_bf)
{
    const int e = blockIdx.x * 256 + threadIdx.x;   // grid exactly E
    const int dst = ei[EE + e];
    const int p = atomicAdd(&cursor[dst], 1);
    src_perm[p] = ei[e];
    const float4* s4 = (const float4*)(ea + (size_t)e * 16);
    const float4 a0 = s4[0], a1 = s4[1], a2 = s4[2], a3 = s4[3];
    union { bf16x8 v; unsigned short u[8]; } o0, o1;
    o0.u[0]=f2bf(a0.x); o0.u[1]=f2bf(a0.y); o0.u[2]=f2bf(a0.z); o0.u[3]=f2bf(a0.w);
    o0.u[4]=f2bf(a1.x); o0.u[5]=f2bf(a1.y); o0.u[6]=f2bf(a1.z); o0.u[7]=f2bf(a1.w);
    o1.u[0]=f2bf(a2.x); o1.u[1]=f2bf(a2.y); o1.u[2]=f2bf(a2.z); o1.u[3]=f2bf(a2.w);
    o1.u[4]=f2bf(a3.x); o1.u[5]=f2bf(a3.y); o1.u[6]=f2bf(a3.z); o1.u[7]=f2bf(a3.w);
    bf16x8* dp = (bf16x8*)(ea_bf + (size_t)p * 16);
    dp[0] = o0.v; dp[1] = o1.v;
}

// ---------------- weight repack to MFMA B-fragment layout ----------------
__global__ void k_pack(const float* __restrict__ W1, const float* __restrict__ W2,
                       unsigned short* __restrict__ Wp1, unsigned short* __restrict__ Wp2)
{
    int t = blockIdx.x * 256 + threadIdx.x;   // grid exactly 2*L*32768
    const int total = LL * 32768;
    if (t < total) {
        const int l = t >> 15, r = t & 32767;
        const int j = r & 7, lane = (r >> 3) & 63, kt = (r >> 9) & 3, nt = r >> 11;
        const int k = kt * 32 + (lane >> 4) * 8 + j;
        const int n = nt * 16 + (lane & 15);
        Wp1[t] = f2bf(W1[(size_t)l * 32768 + k * 256 + n]);
    } else {
        t -= total;
        const int l = t >> 15, r = t & 32767;
        const int j = r & 7, lane = (r >> 3) & 63, kt = (r >> 9) & 7, nt = r >> 12;
        const int k = kt * 32 + (lane >> 4) * 8 + j;
        const int n = nt * 16 + (lane & 15);
        Wp2[t] = f2bf(W2[(size_t)l * 32768 + k * 128 + n]);
    }
}

// ---------------- fused edge-encode + gather + aggregate + GIN-z (bf16 out) ----------------
// R4: register-rotated software pipeline. Depth-2 on src (vector regs, rfl one
// group later so it never waits on a fresh load), depth-1 on h/ea.
// sched_barrier(0) pins the load block above the math so it can't sink.
__global__ __launch_bounds__(256) void k_agg(
    const unsigned short* __restrict__ h_bf, const unsigned short* __restrict__ ea_bf,
    const float* __restrict__ We_l, const float* __restrict__ be_l,
    const float* __restrict__ eps_gin, const int l,
    const int* __restrict__ row_ptr, const int* __restrict__ src_perm,
    unsigned short* __restrict__ z_bf)
{
    const int wv = threadIdx.x >> 6;
    const int v  = blockIdx.x * 4 + wv;      // grid exactly N/4 blocks
    const int lane = threadIdx.x & 63;
    const int c2 = lane * 2;
    float2 w[16];
    #pragma unroll
    for (int f = 0; f < 16; ++f) w[f] = *(const float2*)(We_l + f * 128 + c2);
    const float2 bed = *(const float2*)(be_l + c2);
    const float epsv = 1.0f + eps_gin[l];
    const int kbeg = __builtin_amdgcn_readfirstlane(row_ptr[v]);
    const int kend = __builtin_amdgcn_readfirstlane(row_ptr[v + 1]);
    float2 acc0 = {0.f,0.f}, acc1 = {0.f,0.f}, acc2 = {0.f,0.f}, acc3 = {0.f,0.f};

#define EDGE_DOT(EA, EB, HQ, OUT) do {                                      \
        float ex_ = bed.x, ey_ = bed.y, a_;                                 \
        a_ = BFLO(EA.x); ex_ += a_*w[0].x;  ey_ += a_*w[0].y;               \
        a_ = BFHI(EA.x); ex_ += a_*w[1].x;  ey_ += a_*w[1].y;               \
        a_ = BFLO(EA.y); ex_ += a_*w[2].x;  ey_ += a_*w[2].y;               \
        a_ = BFHI(EA.y); ex_ += a_*w[3].x;  ey_ += a_*w[3].y;               \
        a_ = BFLO(EA.z); ex_ += a_*w[4].x;  ey_ += a_*w[4].y;               \
        a_ = BFHI(EA.z); ex_ += a_*w[5].x;  ey_ += a_*w[5].y;               \
        a_ = BFLO(EA.w); ex_ += a_*w[6].x;  ey_ += a_*w[6].y;               \
        a_ = BFHI(EA.w); ex_ += a_*w[7].x;  ey_ += a_*w[7].y;               \
        a_ = BFLO(EB.x); ex_ += a_*w[8].x;  ey_ += a_*w[8].y;               \
        a_ = BFHI(EB.x); ex_ += a_*w[9].x;  ey_ += a_*w[9].y;               \
        a_ = BFLO(EB.y); ex_ += a_*w[10].x; ey_ += a_*w[10].y;              \
        a_ = BFHI(EB.y); ex_ += a_*w[11].x; ey_ += a_*w[11].y;              \
        a_ = BFLO(EB.z); ex_ += a_*w[12].x; ey_ += a_*w[12].y;              \
        a_ = BFHI(EB.z); ex_ += a_*w[13].x; ey_ += a_*w[13].y;              \
        a_ = BFLO(EB.w); ex_ += a_*w[14].x; ey_ += a_*w[14].y;              \
        a_ = BFHI(EB.w); ex_ += a_*w[15].x; ey_ += a_*w[15].y;              \
        const float mx_ = BFLO(HQ) + ex_, my_ = BFHI(HQ) + ey_;             \
        OUT.x += mx_ > 0.f ? mx_ : 0.f;                                     \
        OUT.y += my_ > 0.f ? my_ : 0.f;                                     \
    } while (0)

    uint4 ce0, ce1, ce2, ce3, ce4, ce5, ce6, ce7;   // current group's ea
    unsigned int ch0, ch1, ch2, ch3;                // current group's h
    int vs0, vs1, vs2, vs3;                         // vector src for NEXT group

    int k = kbeg;
    if (k < kend) {
        const int a0 = __builtin_amdgcn_readfirstlane(src_perm[k]);
        const int a1 = __builtin_amdgcn_readfirstlane(src_perm[k + 1]);
        const int a2 = __builtin_amdgcn_readfirstlane(src_perm[k + 2]);
        const int a3 = __builtin_amdgcn_readfirstlane(src_perm[k + 3]);
        ch0 = *(const unsigned int*)(h_bf + (size_t)a0 * 128 + c2);
        ch1 = *(const unsigned int*)(h_bf + (size_t)a1 * 128 + c2);
        ch2 = *(const unsigned int*)(h_bf + (size_t)a2 * 128 + c2);
        ch3 = *(const unsigned int*)(h_bf + (size_t)a3 * 128 + c2);
        const uint4* ep = (const uint4*)(ea_bf + (size_t)k * 16);
        ce0 = ep[0]; ce1 = ep[1]; ce2 = ep[2]; ce3 = ep[3];
        ce4 = ep[4]; ce5 = ep[5]; ce6 = ep[6]; ce7 = ep[7];
        vs0 = src_perm[k + 4]; vs1 = src_perm[k + 5];
        vs2 = src_perm[k + 6]; vs3 = src_perm[k + 7];
    }
    for (; k < kend; k += 4) {
        // (1) src for group g+2 — vector loads, consumed next iteration
        const int fs0 = src_perm[k + 8],  fs1 = src_perm[k + 9];
        const int fs2 = src_perm[k + 10], fs3 = src_perm[k + 11];
        // (2) h for group g+1 from src loaded last iteration (already arrived)
        const int b0 = __builtin_amdgcn_readfirstlane(vs0);
        const int b1 = __builtin_amdgcn_readfirstlane(vs1);
        const int b2 = __builtin_amdgcn_readfirstlane(vs2);
        const int b3 = __builtin_amdgcn_readfirstlane(vs3);
        const unsigned int nh0 = *(const unsigned int*)(h_bf + (size_t)b0 * 128 + c2);
        const unsigned int nh1 = *(const unsigned int*)(h_bf + (size_t)b1 * 128 + c2);
        const unsigned int nh2 = *(const unsigned int*)(h_bf + (size_t)b2 * 128 + c2);
        const unsigned int nh3 = *(const unsigned int*)(h_bf + (size_t)b3 * 128 + c2);
        // (3) ea for group g+1 (sequential)
        const uint4* np_ = (const uint4*)(ea_bf + (size_t)(k + 4) * 16);
        const uint4 ne0 = np_[0], ne1 = np_[1], ne2 = np_[2], ne3 = np_[3];
        const uint4 ne4 = np_[4], ne5 = np_[5], ne6 = np_[6], ne7 = np_[7];
        __builtin_amdgcn_sched_barrier(0);   // loads stay above the math
        // (4) compute on current group
        EDGE_DOT(ce0, ce1, ch0, acc0);
        if (k + 1 < kend) EDGE_DOT(ce2, ce3, ch1, acc1);
        if (k + 2 < kend) EDGE_DOT(ce4, ce5, ch2, acc2);
        if (k + 3 < kend) EDGE_DOT(ce6, ce7, ch3, acc3);
        // (5) rotate
        ce0=ne0; ce1=ne1; ce2=ne2; ce3=ne3; ce4=ne4; ce5=ne5; ce6=ne6; ce7=ne7;
        ch0=nh0; ch1=nh1; ch2=nh2; ch3=nh3;
        vs0=fs0; vs1=fs1; vs2=fs2; vs3=fs3;
    }
#undef EDGE_DOT
    const unsigned int hv = *(const unsigned int*)(h_bf + (size_t)v * 128 + c2);
    const float zx = epsv * BFLO(hv) + ((acc0.x + acc1.x) + (acc2.x + acc3.x));
    const float zy = epsv * BFHI(hv) + ((acc0.y + acc1.y) + (acc2.y + acc3.y));
    const unsigned int zp = (unsigned int)f2bf(zx) | ((unsigned int)f2bf(zy) << 16);
    *(unsigned int*)(z_bf + (size_t)v * 128 + c2) = zp;
}

// ---------------- GEMM1: t = z @ W1 (64-row tiles), + BN1 partial stats ----------------
__global__ __launch_bounds__(256) void k_gemmB(
    const unsigned short* __restrict__ z_bf,
    const unsigned short* __restrict__ Wp,
    unsigned short* __restrict__ t_bf,
    float* __restrict__ ps, float* __restrict__ pq)
{
    __shared__ __align__(16) unsigned short zs[64 * 136];
    const int tid = threadIdx.x;
    const int r0 = blockIdx.x * 64;
    {
        const int rb = tid >> 4, c0 = (tid & 15) * 8;
        const bf16x8 zero = {0,0,0,0,0,0,0,0};
        #pragma unroll
        for (int r = 0; r < 4; ++r) {
            const int row = r * 16 + rb, g = r0 + row;
            *(bf16x8*)(&zs[row * 136 + c0]) =
                (g < NN) ? *(const bf16x8*)(z_bf + (size_t)g * 128 + c0) : zero;
        }
    }
    __syncthreads();
    const int w = tid >> 6, l6 = tid & 63, m = l6 & 15, quad = l6 >> 4;
    const f32x4 z4 = {0.f, 0.f, 0.f, 0.f};
    f32x4 acc[16] = {z4,z4,z4,z4,z4,z4,z4,z4,z4,z4,z4,z4,z4,z4,z4,z4};
    const bf16x8* Wv = (const bf16x8*)Wp;
    #pragma unroll
    for (int kt = 0; kt < 4; ++kt) {
        const bf16x8 a = *(const bf16x8*)(&zs[(w * 16 + m) * 136 + kt * 32 + quad * 8]);
        #pragma unroll
        for (int ct = 0; ct < 16; ++ct) {
            const bf16x8 b = Wv[(ct * 4 + kt) * 64 + l6];
            acc[ct] = __builtin_amdgcn_mfma_f32_16x16x32_bf16(a, b, acc[ct], 0, 0, 0);
        }
    }
    const int rowb = r0 + w * 16 + quad * 4;
    #pragma unroll
    for (int ct = 0; ct < 16; ++ct) {
        const int col = ct * 16 + m;
        float ssum = 0.f, ssq = 0.f;
        #pragma unroll
        for (int r = 0; r < 4; ++r) {
            const float val = acc[ct][r];
            if (rowb + r < NN) t_bf[(size_t)(rowb + r) * 256 + col] = f2bf(val);
            ssum += val; ssq += val * val;
        }
        ssum += __shfl_xor(ssum, 16); ssum += __shfl_xor(ssum, 32);
        ssq  += __shfl_xor(ssq , 16); ssq  += __shfl_xor(ssq , 32);
        if (quad == 0) {
            ps[(size_t)col * NPART + blockIdx.x * 4 + w] = ssum;
            pq[(size_t)col * NPART + blockIdx.x * 4 + w] = ssq;
        }
    }
}

// ---------------- BN stat fold: per-channel scale/shift ----------------
__global__ void k_bnstat(const float* __restrict__ ps, const float* __restrict__ pq,
                         const float* __restrict__ g, const float* __restrict__ beta,
                         float* __restrict__ sc, float* __restrict__ sh)
{
    const int c = blockIdx.x;
    const int tid = threadIdx.x;   // 256 threads
    const float* pr = ps + (size_t)c * NPART;
    const float* qr = pq + (size_t)c * NPART;
    float s = 0.f, q = 0.f;
    for (int i = tid; i < NPART; i += 256) { s += pr[i]; q += qr[i]; }
    #pragma unroll
    for (int off = 1; off < 64; off <<= 1) { s += __shfl_xor(s, off); q += __shfl_xor(q, off); }
    __shared__ float ls[4], lq[4];
    const int wv = tid >> 6;
    if ((tid & 63) == 0) { ls[wv] = s; lq[wv] = q; }
    __syncthreads();
    if (tid == 0) {
        const float S = ls[0] + ls[1] + ls[2] + ls[3];
        const float Q = lq[0] + lq[1] + lq[2] + lq[3];
        const float mean = S * (1.0f / NN);
        const float var  = Q * (1.0f / NN) - mean * mean;
        const float rs = rsqrtf(var + 1e-5f);
        const float scale = g[c] * rs;
        sc[c] = scale;
        sh[c] = beta[c] - mean * scale;
    }
}

// ---------------- GEMM2: v = relu(BN1(t)) @ W2 (64-row tiles, bf16 out) ----------------
__global__ __launch_bounds__(256) void k_gemmD(
    const unsigned short* __restrict__ t_bf,
    const float* __restrict__ sc1, const float* __restrict__ sh1,
    const unsigned short* __restrict__ Wp,
    unsigned short* __restrict__ vb,
    float* __restrict__ ps, float* __restrict__ pq)
{
    __shared__ __align__(16) unsigned short us[64 * 264];
    const int tid = threadIdx.x;
    const int r0 = blockIdx.x * 64;
    {
        const int rb = tid >> 5, c0 = (tid & 31) * 8;
        const float4 s0 = *(const float4*)(sc1 + c0), s1 = *(const float4*)(sc1 + c0 + 4);
        const float4 b0 = *(const float4*)(sh1 + c0), b1 = *(const float4*)(sh1 + c0 + 4);
        const bf16x8 zero = {0,0,0,0,0,0,0,0};
        #pragma unroll
        for (int rr = 0; rr < 8; ++rr) {
            const int row = rr * 8 + rb, g = r0 + row;
            union { bf16x8 v; unsigned short u[8]; } in, o;
            if (g < NN) {
                in.v = *(const bf16x8*)(t_bf + (size_t)g * 256 + c0);
                float xv;
                xv = bf2f(in.u[0])*s0.x + b0.x; o.u[0] = f2bf(xv > 0.f ? xv : 0.f);
                xv = bf2f(in.u[1])*s0.y + b0.y; o.u[1] = f2bf(xv > 0.f ? xv : 0.f);
                xv = bf2f(in.u[2])*s0.z + b0.z; o.u[2] = f2bf(xv > 0.f ? xv : 0.f);
                xv = bf2f(in.u[3])*s0.w + b0.w; o.u[3] = f2bf(xv > 0.f ? xv : 0.f);
                xv = bf2f(in.u[4])*s1.x + b1.x; o.u[4] = f2bf(xv > 0.f ? xv : 0.f);
                xv = bf2f(in.u[5])*s1.y + b1.y; o.u[5] = f2bf(xv > 0.f ? xv : 0.f);
                xv = bf2f(in.u[6])*s1.z + b1.z; o.u[6] = f2bf(xv > 0.f ? xv : 0.f);
                xv = bf2f(in.u[7])*s1.w + b1.w; o.u[7] = f2bf(xv > 0.f ? xv : 0.f);
            } else {
                o.v = zero;
            }
            *(bf16x8*)(&us[row * 264 + c0]) = o.v;
        }
    }
    __syncthreads();
    const int w = tid >> 6, l6 = tid & 63, m = l6 & 15, quad = l6 >> 4;
    const f32x4 z4 = {0.f, 0.f, 0.f, 0.f};
    f32x4 acc[8] = {z4,z4,z4,z4,z4,z4,z4,z4};
    const bf16x8* Wv = (const bf16x8*)Wp;
    #pragma unroll
    for (int kt = 0; kt < 8; ++kt) {
        const bf16x8 a = *(const bf16x8*)(&us[(w * 16 + m) * 264 + kt * 32 + quad * 8]);
        #pragma unroll
        for (int ct = 0; ct < 8; ++ct) {
            const bf16x8 b = Wv[(ct * 8 + kt) * 64 + l6];
            acc[ct] = __builtin_amdgcn_mfma_f32_16x16x32_bf16(a, b, acc[ct], 0, 0, 0);
        }
    }
    const int rowb = r0 + w * 16 + quad * 4;
    #pragma unroll
    for (int ct = 0; ct < 8; ++ct) {
        const int col = ct * 16 + m;
        float ssum = 0.f, ssq = 0.f;
        #pragma unroll
        for (int r = 0; r < 4; ++r) {
            const float val = acc[ct][r];
            if (rowb + r < NN) vb[(size_t)(rowb + r) * 128 + col] = f2bf(val);
            ssum += val; ssq += val * val;
        }
        ssum += __shfl_xor(ssum, 16); ssum += __shfl_xor(ssum, 32);
        ssq  += __shfl_xor(ssq , 16); ssq  += __shfl_xor(ssq , 32);
        if (quad == 0) {
            ps[(size_t)col * NPART + blockIdx.x * 4 + w] = ssum;
            pq[(size_t)col * NPART + blockIdx.x * 4 + w] = ssq;
        }
    }
}

// ---------------- BN2 + optional relu + residual (+ bf16 mirror), 8 ch/thread ----------------
__global__ void k_fin(const unsigned short* __restrict__ vb,
                      const float* __restrict__ sc2, const float* __restrict__ sh2,
                      float* __restrict__ h, unsigned short* __restrict__ h_bf,
                      const int do_relu)
{
    const int t = blockIdx.x * 256 + threadIdx.x;   // grid exactly N*128/8
    const int base = t * 8;
    const int c = base & 127;
    union { bf16x8 v; unsigned short u[8]; } in, ob;
    in.v = *(const bf16x8*)(vb + base);
    const float4 s0 = *(const float4*)(sc2 + c), s1 = *(const float4*)(sc2 + c + 4);
    const float4 b0 = *(const float4*)(sh2 + c), b1 = *(const float4*)(sh2 + c + 4);
    float4 h0 = *(const float4*)(h + base), h1 = *(const float4*)(h + base + 4);
    float z;
    z = bf2f(in.u[0])*s0.x + b0.x; if (do_relu) z = z > 0.f ? z : 0.f; h0.x += z;
    z = bf2f(in.u[1])*s0.y + b0.y; if (do_relu) z = z > 0.f ? z : 0.f; h0.y += z;
    z = bf2f(in.u[2])*s0.z + b0.z; if (do_relu) z = z > 0.f ? z : 0.f; h0.z += z;
    z = bf2f(in.u[3])*s0.w + b0.w; if (do_relu) z = z > 0.f ? z : 0.f; h0.w += z;
    z = bf2f(in.u[4])*s1.x + b1.x; if (do_relu) z = z > 0.f ? z : 0.f; h1.x += z;
    z = bf2f(in.u[5])*s1.y + b1.y; if (do_relu) z = z > 0.f ? z : 0.f; h1.y += z;
    z = bf2f(in.u[6])*s1.z + b1.z; if (do_relu) z = z > 0.f ? z : 0.f; h1.z += z;
    z = bf2f(in.u[7])*s1.w + b1.w; if (do_relu) z = z > 0.f ? z : 0.f; h1.w += z;
    *(float4*)(h + base) = h0;
    *(float4*)(h + base + 4) = h1;
    ob.u[0]=f2bf(h0.x); ob.u[1]=f2bf(h0.y); ob.u[2]=f2bf(h0.z); ob.u[3]=f2bf(h0.w);
    ob.u[4]=f2bf(h1.x); ob.u[5]=f2bf(h1.y); ob.u[6]=f2bf(h1.z); ob.u[7]=f2bf(h1.w);
    *(bf16x8*)(h_bf + base) = ob.v;
}

extern "C" void kernel_launch(void* const* d_in, const int* in_sizes, int n_in,
                              void* d_out, int out_size, void* d_ws, size_t ws_size,
                              hipStream_t stream)
{
    const float* x       = (const float*)d_in[0];
    const int*   ei      = (const int*)  d_in[1];
    const float* ea      = (const float*)d_in[2];
    const float* W_node  = (const float*)d_in[3];
    const float* b_node  = (const float*)d_in[4];
    const float* We      = (const float*)d_in[5];
    const float* be      = (const float*)d_in[6];
    const float* eps_gin = (const float*)d_in[7];
    const float* W1      = (const float*)d_in[8];
    // d_in[9] = b1: cancels exactly under BN1 (mean subtraction)
    const float* g1      = (const float*)d_in[10];
    const float* beta1   = (const float*)d_in[11];
    const float* W2      = (const float*)d_in[12];
    // d_in[13] = b2: cancels exactly under BN2
    const float* g_bn    = (const float*)d_in[14];
    const float* beta_bn = (const float*)d_in[15];

    float* h = (float*)d_out;

    char* W = (char*)d_ws;
    int*   counts   = (int*)  (W + 0);             // 200000 B (also fill cursor)
    int*   row_ptr  = (int*)  (W + 200000);        // 200004 B → next at 400064
    float* sc1      = (float*)(W + 400064);        // 1024 B
    float* sh1      = (float*)(W + 401088);        // 1024 B
    float* sc2      = (float*)(W + 402112);        // 512 B
    float* sh2      = (float*)(W + 402624);        // 512 B
    float* ps1      = (float*)(W + 403136);        // 256*3128*4 = 3203072 B
    float* pq1      = (float*)(W + 3606208);       // 3203072 B
    float* ps2      = (float*)(W + 6809280);       // 128*3128*4 = 1601536 B
    float* pq2      = (float*)(W + 8410816);       // 1601536 B
    int*   src_perm = (int*)  (W + 10012352);      // (EE+16)*4 = 3200064 B
    unsigned short* ea_bf = (unsigned short*)(W + 13212416); // EE*32+512 = 25600512 B
    unsigned short* Wp1   = (unsigned short*)(W + 38812928); // 327680 B
    unsigned short* Wp2   = (unsigned short*)(W + 39140608); // 327680 B
    unsigned short* z_bf  = (unsigned short*)(W + 39468288); // 12800000 B (vb alias)
    unsigned short* t_bf  = (unsigned short*)(W + 52268288); // 25600000 B
    unsigned short* h_bf  = (unsigned short*)(W + 77868288); // 12800000 B → total ~90.7 MB
    unsigned short* vb    = z_bf;  // safe alias: z_bf dead after gemmB, vb born in gemmD

    (void)hipMemsetAsync(counts, 0, 200000, stream);
    (void)hipMemsetAsync(src_perm + EE, 0, 64, stream);   // pipeline overrun pad

    k_node_enc<<<dim3(NN * DD / 256), dim3(256), 0, stream>>>(x, W_node, b_node, h, h_bf);
    k_count<<<dim3(EE / 256), dim3(256), 0, stream>>>(ei, counts);
    k_scan<<<dim3(1), dim3(1024), 0, stream>>>(counts, row_ptr);
    k_fill<<<dim3(EE / 256), dim3(256), 0, stream>>>(ei, ea, counts, src_perm, ea_bf);
    k_pack<<<dim3(2 * LL * 32768 / 256), dim3(256), 0, stream>>>(W1, W2, Wp1, Wp2);

    for (int l = 0; l < LL; ++l) {
        k_agg<<<dim3(NN / 4), dim3(256), 0, stream>>>(
            h_bf, ea_bf, We + (size_t)l * FF * DD, be + (size_t)l * DD,
            eps_gin, l, row_ptr, src_perm, z_bf);
        k_gemmB<<<dim3(NB), dim3(256), 0, stream>>>(
            z_bf, Wp1 + (size_t)l * 32768, t_bf, ps1, pq1);
        k_bnstat<<<dim3(256), dim3(256), 0, stream>>>(
            ps1, pq1, g1 + (size_t)l * 256, beta1 + (size_t)l * 256, sc1, sh1);
        k_gemmD<<<dim3(NB), dim3(256), 0, stream>>>(
            t_bf, sc1, sh1, Wp2 + (size_t)l * 32768, vb, ps2, pq2);
        k_bnstat<<<dim3(128), dim3(256), 0, stream>>>(
            ps2, pq2, g_bn + (size_t)l * 128, beta_bn + (size_t)l * 128, sc2, sh2);
        k_fin<<<dim3(NN * DD / 8 / 256), dim3(256), 0, stream>>>(
            vb, sc2, sh2, h, h_bf, (l < LL - 1) ? 1 : 0);
    }
}

// Round 6
// 927.252 us; speedup vs baseline: 1.1336x; 1.1336x over previous
//
#include <hip/hip_runtime.h>
#include <hip/hip_bf16.h>

// Problem constants
#define NN 50000
#define EE 800000
#define DD 128
#define FF 16
#define LL 5
#define NB 782            // ceil(50000/64) row-tile blocks in GEMMs

typedef __attribute__((ext_vector_type(8))) short bf16x8;
typedef __attribute__((ext_vector_type(4))) float f32x4;

__device__ __forceinline__ unsigned short f2bf(float f) {
    union { float f; unsigned int u; } v; v.f = f;
    unsigned int u = v.u;
    unsigned int r = (u + 0x7fffu + ((u >> 16) & 1u)) >> 16;
    return (unsigned short)r;
}
__device__ __forceinline__ float bf2f(unsigned short s) {
    union { unsigned int u; float f; } v; v.u = ((unsigned int)s) << 16;
    return v.f;
}
#define BFLO(u) __uint_as_float((unsigned int)(u) << 16)
#define BFHI(u) __uint_as_float((unsigned int)(u) & 0xffff0000u)

// ---------------- node encoder: h = x @ W_node + b_node (+ bf16 mirror) ----------------
__global__ void k_node_enc(const float* __restrict__ x, const float* __restrict__ Wn,
                           const float* __restrict__ bn, float* __restrict__ h,
                           unsigned short* __restrict__ h_bf)
{
    const int t = blockIdx.x * 256 + threadIdx.x;   // grid exactly N*128
    const int i = t >> 7, d = t & 127;
    const float4* x4 = (const float4*)(x + (size_t)i * 16);
    float4 a0 = x4[0], a1 = x4[1], a2 = x4[2], a3 = x4[3];
    float acc = bn[d];
    acc += a0.x*Wn[0*128+d] + a0.y*Wn[1*128+d] + a0.z*Wn[2*128+d] + a0.w*Wn[3*128+d];
    acc += a1.x*Wn[4*128+d] + a1.y*Wn[5*128+d] + a1.z*Wn[6*128+d] + a1.w*Wn[7*128+d];
    acc += a2.x*Wn[8*128+d] + a2.y*Wn[9*128+d] + a2.z*Wn[10*128+d] + a2.w*Wn[11*128+d];
    acc += a3.x*Wn[12*128+d] + a3.y*Wn[13*128+d] + a3.z*Wn[14*128+d] + a3.w*Wn[15*128+d];
    h[t] = acc;
    h_bf[t] = f2bf(acc);
}

// ---------------- CSR build ----------------
__global__ void k_count(const int* __restrict__ ei, int* __restrict__ counts)
{
    const int e = blockIdx.x * 256 + threadIdx.x;   // grid exactly E
    atomicAdd(&counts[ei[EE + e]], 1);
}

__global__ __launch_bounds__(1024) void k_scan(int* __restrict__ counts, int* __restrict__ row_ptr)
{
    __shared__ int wsum[16];
    __shared__ int carry;
    const int tid = threadIdx.x, lane = tid & 63, w = tid >> 6;
    if (tid == 0) carry = 0;
    __syncthreads();
    for (int base = 0; base < NN; base += 1024) {
        const int i = base + tid;
        const int v = (i < NN) ? counts[i] : 0;
        int x = v;
        #pragma unroll
        for (int off = 1; off < 64; off <<= 1) {
            const int t = __shfl_up(x, off);
            if (lane >= off) x += t;
        }
        if (lane == 63) wsum[w] = x;
        __syncthreads();
        int woff = 0, total = 0;
        #pragma unroll
        for (int j = 0; j < 16; ++j) { const int s = wsum[j]; total += s; if (j < w) woff += s; }
        const int ex = carry + woff + x - v;
        if (i < NN) { row_ptr[i] = ex; counts[i] = ex; }
        __syncthreads();
        if (tid == 0) carry += total;
        __syncthreads();
    }
    if (tid == 0) row_ptr[NN] = carry;
}

// Fill CSR slots AND permute+convert edge features to bf16 in CSR order.
__global__ void k_fill(const int* __restrict__ ei, const float* __restrict__ ea,
                       int* __restrict__ cursor, int* __restrict__ src_perm,
                       unsigned short* __restrict__ ea_bf)
{
    const int e = blockIdx.x * 256 + threadIdx.x;   // grid exactly E
    const int dst = ei[EE + e];
    const int p = atomicAdd(&cursor[dst], 1);
    src_perm[p] = ei[e];
    const float4* s4 = (const float4*)(ea + (size_t)e * 16);
    const float4 a0 = s4[0], a1 = s4[1], a2 = s4[2], a3 = s4[3];
    union { bf16x8 v; unsigned short u[8]; } o0, o1;
    o0.u[0]=f2bf(a0.x); o0.u[1]=f2bf(a0.y); o0.u[2]=f2bf(a0.z); o0.u[3]=f2bf(a0.w);
    o0.u[4]=f2bf(a1.x); o0.u[5]=f2bf(a1.y); o0.u[6]=f2bf(a1.z); o0.u[7]=f2bf(a1.w);
    o1.u[0]=f2bf(a2.x); o1.u[1]=f2bf(a2.y); o1.u[2]=f2bf(a2.z); o1.u[3]=f2bf(a2.w);
    o1.u[4]=f2bf(a3.x); o1.u[5]=f2bf(a3.y); o1.u[6]=f2bf(a3.z); o1.u[7]=f2bf(a3.w);
    bf16x8* dp = (bf16x8*)(ea_bf + (size_t)p * 16);
    dp[0] = o0.v; dp[1] = o1.v;
}

// ---------------- weight repack to MFMA B-fragment layout ----------------
__global__ void k_pack(const float* __restrict__ W1, const float* __restrict__ W2,
                       unsigned short* __restrict__ Wp1, unsigned short* __restrict__ Wp2)
{
    int t = blockIdx.x * 256 + threadIdx.x;   // grid exactly 2*L*32768
    const int total = LL * 32768;
    if (t < total) {
        const int l = t >> 15, r = t & 32767;
        const int j = r & 7, lane = (r >> 3) & 63, kt = (r >> 9) & 3, nt = r >> 11;
        const int k = kt * 32 + (lane >> 4) * 8 + j;
        const int n = nt * 16 + (lane & 15);
        Wp1[t] = f2bf(W1[(size_t)l * 32768 + k * 256 + n]);
    } else {
        t -= total;
        const int l = t >> 15, r = t & 32767;
        const int j = r & 7, lane = (r >> 3) & 63, kt = (r >> 9) & 7, nt = r >> 12;
        const int k = kt * 32 + (lane >> 4) * 8 + j;
        const int n = nt * 16 + (lane & 15);
        Wp2[t] = f2bf(W2[(size_t)l * 32768 + k * 128 + n]);
    }
}

// ---------------- fused edge-encode + gather + aggregate + GIN-z (bf16 out) ----------------
__global__ __launch_bounds__(256) void k_agg(
    const unsigned short* __restrict__ h_bf, const unsigned short* __restrict__ ea_bf,
    const float* __restrict__ We_l, const float* __restrict__ be_l,
    const float* __restrict__ eps_gin, const int l,
    const int* __restrict__ row_ptr, const int* __restrict__ src_perm,
    unsigned short* __restrict__ z_bf)
{
    const int wv = threadIdx.x >> 6;
    const int v  = blockIdx.x * 4 + wv;      // grid exactly N/4 blocks
    const int lane = threadIdx.x & 63;
    const int c2 = lane * 2;
    float2 w[16];
    #pragma unroll
    for (int f = 0; f < 16; ++f) w[f] = *(const float2*)(We_l + f * 128 + c2);
    const float2 bed = *(const float2*)(be_l + c2);
    const float epsv = 1.0f + eps_gin[l];
    const int kbeg = __builtin_amdgcn_readfirstlane(row_ptr[v]);
    const int kend = __builtin_amdgcn_readfirstlane(row_ptr[v + 1]);
    float2 acc0 = {0.f,0.f}, acc1 = {0.f,0.f}, acc2 = {0.f,0.f}, acc3 = {0.f,0.f};

#define EDGE_DOT(EA, EB, HQ, OUT) do {                                      \
        float ex_ = bed.x, ey_ = bed.y, a_;                                 \
        a_ = BFLO(EA.x); ex_ += a_*w[0].x;  ey_ += a_*w[0].y;               \
        a_ = BFHI(EA.x); ex_ += a_*w[1].x;  ey_ += a_*w[1].y;               \
        a_ = BFLO(EA.y); ex_ += a_*w[2].x;  ey_ += a_*w[2].y;               \
        a_ = BFHI(EA.y); ex_ += a_*w[3].x;  ey_ += a_*w[3].y;               \
        a_ = BFLO(EA.z); ex_ += a_*w[4].x;  ey_ += a_*w[4].y;               \
        a_ = BFHI(EA.z); ex_ += a_*w[5].x;  ey_ += a_*w[5].y;               \
        a_ = BFLO(EA.w); ex_ += a_*w[6].x;  ey_ += a_*w[6].y;               \
        a_ = BFHI(EA.w); ex_ += a_*w[7].x;  ey_ += a_*w[7].y;               \
        a_ = BFLO(EB.x); ex_ += a_*w[8].x;  ey_ += a_*w[8].y;               \
        a_ = BFHI(EB.x); ex_ += a_*w[9].x;  ey_ += a_*w[9].y;               \
        a_ = BFLO(EB.y); ex_ += a_*w[10].x; ey_ += a_*w[10].y;              \
        a_ = BFHI(EB.y); ex_ += a_*w[11].x; ey_ += a_*w[11].y;              \
        a_ = BFLO(EB.z); ex_ += a_*w[12].x; ey_ += a_*w[12].y;              \
        a_ = BFHI(EB.z); ex_ += a_*w[13].x; ey_ += a_*w[13].y;              \
        a_ = BFLO(EB.w); ex_ += a_*w[14].x; ey_ += a_*w[14].y;              \
        a_ = BFHI(EB.w); ex_ += a_*w[15].x; ey_ += a_*w[15].y;              \
        const float mx_ = BFLO(HQ) + ex_, my_ = BFHI(HQ) + ey_;             \
        OUT.x += mx_ > 0.f ? mx_ : 0.f;                                     \
        OUT.y += my_ > 0.f ? my_ : 0.f;                                     \
    } while (0)

    uint4 ce0, ce1, ce2, ce3, ce4, ce5, ce6, ce7;
    unsigned int ch0, ch1, ch2, ch3;
    int vs0, vs1, vs2, vs3;

    int k = kbeg;
    if (k < kend) {
        const int a0 = __builtin_amdgcn_readfirstlane(src_perm[k]);
        const int a1 = __builtin_amdgcn_readfirstlane(src_perm[k + 1]);
        const int a2 = __builtin_amdgcn_readfirstlane(src_perm[k + 2]);
        const int a3 = __builtin_amdgcn_readfirstlane(src_perm[k + 3]);
        ch0 = *(const unsigned int*)(h_bf + (size_t)a0 * 128 + c2);
        ch1 = *(const unsigned int*)(h_bf + (size_t)a1 * 128 + c2);
        ch2 = *(const unsigned int*)(h_bf + (size_t)a2 * 128 + c2);
        ch3 = *(const unsigned int*)(h_bf + (size_t)a3 * 128 + c2);
        const uint4* ep = (const uint4*)(ea_bf + (size_t)k * 16);
        ce0 = ep[0]; ce1 = ep[1]; ce2 = ep[2]; ce3 = ep[3];
        ce4 = ep[4]; ce5 = ep[5]; ce6 = ep[6]; ce7 = ep[7];
        vs0 = src_perm[k + 4]; vs1 = src_perm[k + 5];
        vs2 = src_perm[k + 6]; vs3 = src_perm[k + 7];
    }
    for (; k < kend; k += 4) {
        const int fs0 = src_perm[k + 8],  fs1 = src_perm[k + 9];
        const int fs2 = src_perm[k + 10], fs3 = src_perm[k + 11];
        const int b0 = __builtin_amdgcn_readfirstlane(vs0);
        const int b1 = __builtin_amdgcn_readfirstlane(vs1);
        const int b2 = __builtin_amdgcn_readfirstlane(vs2);
        const int b3 = __builtin_amdgcn_readfirstlane(vs3);
        const unsigned int nh0 = *(const unsigned int*)(h_bf + (size_t)b0 * 128 + c2);
        const unsigned int nh1 = *(const unsigned int*)(h_bf + (size_t)b1 * 128 + c2);
        const unsigned int nh2 = *(const unsigned int*)(h_bf + (size_t)b2 * 128 + c2);
        const unsigned int nh3 = *(const unsigned int*)(h_bf + (size_t)b3 * 128 + c2);
        const uint4* np_ = (const uint4*)(ea_bf + (size_t)(k + 4) * 16);
        const uint4 ne0 = np_[0], ne1 = np_[1], ne2 = np_[2], ne3 = np_[3];
        const uint4 ne4 = np_[4], ne5 = np_[5], ne6 = np_[6], ne7 = np_[7];
        __builtin_amdgcn_sched_barrier(0);
        EDGE_DOT(ce0, ce1, ch0, acc0);
        if (k + 1 < kend) EDGE_DOT(ce2, ce3, ch1, acc1);
        if (k + 2 < kend) EDGE_DOT(ce4, ce5, ch2, acc2);
        if (k + 3 < kend) EDGE_DOT(ce6, ce7, ch3, acc3);
        ce0=ne0; ce1=ne1; ce2=ne2; ce3=ne3; ce4=ne4; ce5=ne5; ce6=ne6; ce7=ne7;
        ch0=nh0; ch1=nh1; ch2=nh2; ch3=nh3;
        vs0=fs0; vs1=fs1; vs2=fs2; vs3=fs3;
    }
#undef EDGE_DOT
    const unsigned int hv = *(const unsigned int*)(h_bf + (size_t)v * 128 + c2);
    const float zx = epsv * BFLO(hv) + ((acc0.x + acc1.x) + (acc2.x + acc3.x));
    const float zy = epsv * BFHI(hv) + ((acc0.y + acc1.y) + (acc2.y + acc3.y));
    const unsigned int zp = (unsigned int)f2bf(zx) | ((unsigned int)f2bf(zy) << 16);
    *(unsigned int*)(z_bf + (size_t)v * 128 + c2) = zp;
}

// ---------------- GEMM1: t = z @ W1. B in registers; wave owns 64-col stripe. ----------------
// Col sums/sumsq accumulated in-lane, one atomicAdd per col per block.
__global__ __launch_bounds__(256) void k_gemmB(
    const unsigned short* __restrict__ z_bf,
    const unsigned short* __restrict__ Wp,
    unsigned short* __restrict__ t_bf,
    float* __restrict__ ps1, float* __restrict__ pq1)
{
    const int tid = threadIdx.x;
    const int w = tid >> 6, l6 = tid & 63, m = l6 & 15, quad = l6 >> 4;
    const int r0 = blockIdx.x * 64;
    const bf16x8* Wv = (const bf16x8*)Wp;
    bf16x8 b[4][4];                      // wave's B stripe, loaded once
    #pragma unroll
    for (int ct = 0; ct < 4; ++ct)
        #pragma unroll
        for (int kt = 0; kt < 4; ++kt)
            b[ct][kt] = Wv[((w * 4 + ct) * 4 + kt) * 64 + l6];

    const bf16x8 zero8 = {0,0,0,0,0,0,0,0};
    const f32x4 z4 = {0.f, 0.f, 0.f, 0.f};
    float rs_[4] = {0.f,0.f,0.f,0.f}, rq_[4] = {0.f,0.f,0.f,0.f};

    bf16x8 a[4], an[4];
    {
        const int row = r0 + m;
        #pragma unroll
        for (int kt = 0; kt < 4; ++kt)
            a[kt] = (row < NN) ? *(const bf16x8*)(z_bf + (size_t)row * 128 + kt * 32 + quad * 8) : zero8;
    }
    #pragma unroll
    for (int rt = 0; rt < 4; ++rt) {
        if (rt < 3) {
            const int row = r0 + (rt + 1) * 16 + m;
            #pragma unroll
            for (int kt = 0; kt < 4; ++kt)
                an[kt] = (row < NN) ? *(const bf16x8*)(z_bf + (size_t)row * 128 + kt * 32 + quad * 8) : zero8;
        }
        f32x4 acc[4] = {z4, z4, z4, z4};
        #pragma unroll
        for (int kt = 0; kt < 4; ++kt)
            #pragma unroll
            for (int ct = 0; ct < 4; ++ct)
                acc[ct] = __builtin_amdgcn_mfma_f32_16x16x32_bf16(a[kt], b[ct][kt], acc[ct], 0, 0, 0);
        const int rowb = r0 + rt * 16 + quad * 4;
        #pragma unroll
        for (int ct = 0; ct < 4; ++ct) {
            const int col = w * 64 + ct * 16 + m;
            #pragma unroll
            for (int r = 0; r < 4; ++r) {
                const float val = acc[ct][r];
                if (rowb + r < NN) t_bf[(size_t)(rowb + r) * 256 + col] = f2bf(val);
                rs_[ct] += val; rq_[ct] += val * val;
            }
        }
        #pragma unroll
        for (int kt = 0; kt < 4; ++kt) a[kt] = an[kt];
    }
    #pragma unroll
    for (int ct = 0; ct < 4; ++ct) {
        float ss = rs_[ct], sq = rq_[ct];
        ss += __shfl_xor(ss, 16); ss += __shfl_xor(ss, 32);
        sq += __shfl_xor(sq, 16); sq += __shfl_xor(sq, 32);
        if (quad == 0) {
            const int col = w * 64 + ct * 16 + m;
            atomicAdd(&ps1[col], ss);
            atomicAdd(&pq1[col], sq);
        }
    }
}

// ---------------- GEMM2: v = relu(BN1(t)) @ W2. BN folded in-block; B in regs. ----------------
__global__ __launch_bounds__(256) void k_gemmD(
    const unsigned short* __restrict__ t_bf,
    const float* __restrict__ ps1, const float* __restrict__ pq1,
    const float* __restrict__ g1, const float* __restrict__ be1,
    const unsigned short* __restrict__ Wp,
    unsigned short* __restrict__ vb,
    float* __restrict__ ps2, float* __restrict__ pq2)
{
    __shared__ __align__(16) unsigned short us[64 * 264];
    __shared__ __align__(16) float scf[256], shf[256];
    const int tid = threadIdx.x;
    {   // fold global column sums -> scale/shift (256 threads, 1 col each)
        const float mean = ps1[tid] * (1.0f / NN);
        const float var  = pq1[tid] * (1.0f / NN) - mean * mean;
        const float sc = g1[tid] * rsqrtf(var + 1e-5f);
        scf[tid] = sc;
        shf[tid] = be1[tid] - mean * sc;
    }
    __syncthreads();
    const int r0 = blockIdx.x * 64;
    {
        const int rb = tid >> 5, c0 = (tid & 31) * 8;
        const float4 s0 = *(const float4*)(scf + c0), s1 = *(const float4*)(scf + c0 + 4);
        const float4 b0 = *(const float4*)(shf + c0), b1 = *(const float4*)(shf + c0 + 4);
        const bf16x8 zero = {0,0,0,0,0,0,0,0};
        #pragma unroll
        for (int rr = 0; rr < 8; ++rr) {
            const int row = rr * 8 + rb, g = r0 + row;
            union { bf16x8 v; unsigned short u[8]; } in, o;
            if (g < NN) {
                in.v = *(const bf16x8*)(t_bf + (size_t)g * 256 + c0);
                float xv;
                xv = bf2f(in.u[0])*s0.x + b0.x; o.u[0] = f2bf(xv > 0.f ? xv : 0.f);
                xv = bf2f(in.u[1])*s0.y + b0.y; o.u[1] = f2bf(xv > 0.f ? xv : 0.f);
                xv = bf2f(in.u[2])*s0.z + b0.z; o.u[2] = f2bf(xv > 0.f ? xv : 0.f);
                xv = bf2f(in.u[3])*s0.w + b0.w; o.u[3] = f2bf(xv > 0.f ? xv : 0.f);
                xv = bf2f(in.u[4])*s1.x + b1.x; o.u[4] = f2bf(xv > 0.f ? xv : 0.f);
                xv = bf2f(in.u[5])*s1.y + b1.y; o.u[5] = f2bf(xv > 0.f ? xv : 0.f);
                xv = bf2f(in.u[6])*s1.z + b1.z; o.u[6] = f2bf(xv > 0.f ? xv : 0.f);
                xv = bf2f(in.u[7])*s1.w + b1.w; o.u[7] = f2bf(xv > 0.f ? xv : 0.f);
            } else {
                o.v = zero;
            }
            *(bf16x8*)(&us[row * 264 + c0]) = o.v;
        }
    }
    __syncthreads();
    const int w = tid >> 6, l6 = tid & 63, m = l6 & 15, quad = l6 >> 4;
    const bf16x8* Wv = (const bf16x8*)Wp;
    bf16x8 b[2][8];                      // wave's 32-col B stripe
    #pragma unroll
    for (int ct = 0; ct < 2; ++ct)
        #pragma unroll
        for (int kt = 0; kt < 8; ++kt)
            b[ct][kt] = Wv[((w * 2 + ct) * 8 + kt) * 64 + l6];

    const f32x4 z4 = {0.f, 0.f, 0.f, 0.f};
    float rs_[2] = {0.f,0.f}, rq_[2] = {0.f,0.f};
    #pragma unroll
    for (int rt = 0; rt < 4; ++rt) {
        bf16x8 a[8];
        #pragma unroll
        for (int kt = 0; kt < 8; ++kt)
            a[kt] = *(const bf16x8*)(&us[(rt * 16 + m) * 264 + kt * 32 + quad * 8]);
        f32x4 acc[2] = {z4, z4};
        #pragma unroll
        for (int kt = 0; kt < 8; ++kt)
            #pragma unroll
            for (int ct = 0; ct < 2; ++ct)
                acc[ct] = __builtin_amdgcn_mfma_f32_16x16x32_bf16(a[kt], b[ct][kt], acc[ct], 0, 0, 0);
        const int rowb = r0 + rt * 16 + quad * 4;
        #pragma unroll
        for (int ct = 0; ct < 2; ++ct) {
            const int col = w * 32 + ct * 16 + m;
            #pragma unroll
            for (int r = 0; r < 4; ++r) {
                const float val = acc[ct][r];
                if (rowb + r < NN) vb[(size_t)(rowb + r) * 128 + col] = f2bf(val);
                rs_[ct] += val; rq_[ct] += val * val;
            }
        }
    }
    #pragma unroll
    for (int ct = 0; ct < 2; ++ct) {
        float ss = rs_[ct], sq = rq_[ct];
        ss += __shfl_xor(ss, 16); ss += __shfl_xor(ss, 32);
        sq += __shfl_xor(sq, 16); sq += __shfl_xor(sq, 32);
        if (quad == 0) {
            const int col = w * 32 + ct * 16 + m;
            atomicAdd(&ps2[col], ss);
            atomicAdd(&pq2[col], sq);
        }
    }
}

// ---------------- BN2 + optional relu + residual (+ bf16 mirror), 8 ch/thread ----------------
__global__ void k_fin(const unsigned short* __restrict__ vb,
                      const float* __restrict__ ps2, const float* __restrict__ pq2,
                      const float* __restrict__ g2, const float* __restrict__ be2,
                      float* __restrict__ h, unsigned short* __restrict__ h_bf,
                      const int do_relu)
{
    __shared__ __align__(16) float scf[128], shf[128];
    const int tid = threadIdx.x;
    if (tid < 128) {
        const float mean = ps2[tid] * (1.0f / NN);
        const float var  = pq2[tid] * (1.0f / NN) - mean * mean;
        const float sc = g2[tid] * rsqrtf(var + 1e-5f);
        scf[tid] = sc;
        shf[tid] = be2[tid] - mean * sc;
    }
    __syncthreads();
    const int t = blockIdx.x * 256 + tid;   // grid exactly N*128/8
    const int base = t * 8;
    const int c = base & 127;
    union { bf16x8 v; unsigned short u[8]; } in, ob;
    in.v = *(const bf16x8*)(vb + base);
    const float4 s0 = *(const float4*)(scf + c), s1 = *(const float4*)(scf + c + 4);
    const float4 b0 = *(const float4*)(shf + c), b1 = *(const float4*)(shf + c + 4);
    float4 h0 = *(const float4*)(h + base), h1 = *(const float4*)(h + base + 4);
    float z;
    z = bf2f(in.u[0])*s0.x + b0.x; if (do_relu) z = z > 0.f ? z : 0.f; h0.x += z;
    z = bf2f(in.u[1])*s0.y + b0.y; if (do_relu) z = z > 0.f ? z : 0.f; h0.y += z;
    z = bf2f(in.u[2])*s0.z + b0.z; if (do_relu) z = z > 0.f ? z : 0.f; h0.z += z;
    z = bf2f(in.u[3])*s0.w + b0.w; if (do_relu) z = z > 0.f ? z : 0.f; h0.w += z;
    z = bf2f(in.u[4])*s1.x + b1.x; if (do_relu) z = z > 0.f ? z : 0.f; h1.x += z;
    z = bf2f(in.u[5])*s1.y + b1.y; if (do_relu) z = z > 0.f ? z : 0.f; h1.y += z;
    z = bf2f(in.u[6])*s1.z + b1.z; if (do_relu) z = z > 0.f ? z : 0.f; h1.z += z;
    z = bf2f(in.u[7])*s1.w + b1.w; if (do_relu) z = z > 0.f ? z : 0.f; h1.w += z;
    *(float4*)(h + base) = h0;
    *(float4*)(h + base + 4) = h1;
    ob.u[0]=f2bf(h0.x); ob.u[1]=f2bf(h0.y); ob.u[2]=f2bf(h0.z); ob.u[3]=f2bf(h0.w);
    ob.u[4]=f2bf(h1.x); ob.u[5]=f2bf(h1.y); ob.u[6]=f2bf(h1.z); ob.u[7]=f2bf(h1.w);
    *(bf16x8*)(h_bf + base) = ob.v;
}

extern "C" void kernel_launch(void* const* d_in, const int* in_sizes, int n_in,
                              void* d_out, int out_size, void* d_ws, size_t ws_size,
                              hipStream_t stream)
{
    const float* x       = (const float*)d_in[0];
    const int*   ei      = (const int*)  d_in[1];
    const float* ea      = (const float*)d_in[2];
    const float* W_node  = (const float*)d_in[3];
    const float* b_node  = (const float*)d_in[4];
    const float* We      = (const float*)d_in[5];
    const float* be      = (const float*)d_in[6];
    const float* eps_gin = (const float*)d_in[7];
    const float* W1      = (const float*)d_in[8];
    // d_in[9] = b1: cancels exactly under BN1 (mean subtraction)
    const float* g1      = (const float*)d_in[10];
    const float* beta1   = (const float*)d_in[11];
    const float* W2      = (const float*)d_in[12];
    // d_in[13] = b2: cancels exactly under BN2
    const float* g_bn    = (const float*)d_in[14];
    const float* beta_bn = (const float*)d_in[15];

    float* h = (float*)d_out;

    char* W = (char*)d_ws;
    int*   counts   = (int*)  (W + 0);             // 200000 B (also fill cursor)
    int*   row_ptr  = (int*)  (W + 200000);        // 200004 B → pad to 400064
    float* stats    = (float*)(W + 400064);        // 768 floats = 3072 B
    float* ps1 = stats, *pq1 = stats + 256, *ps2 = stats + 512, *pq2 = stats + 640;
    int*   src_perm = (int*)  (W + 403136);        // (EE+16)*4 = 3200064 B
    unsigned short* ea_bf = (unsigned short*)(W + 3603200);  // EE*32+512 = 25600512 B
    unsigned short* Wp1   = (unsigned short*)(W + 29203712); // 327680 B
    unsigned short* Wp2   = (unsigned short*)(W + 29531392); // 327680 B
    unsigned short* z_bf  = (unsigned short*)(W + 29859072); // 12800000 B (vb alias)
    unsigned short* t_bf  = (unsigned short*)(W + 42659072); // 25600000 B
    unsigned short* h_bf  = (unsigned short*)(W + 68259072); // 12800000 B → total ~81.1 MB
    unsigned short* vb    = z_bf;  // safe alias: z_bf dead after gemmB, vb born in gemmD

    (void)hipMemsetAsync(counts, 0, 200000, stream);
    (void)hipMemsetAsync(src_perm + EE, 0, 64, stream);   // pipeline overrun pad

    k_node_enc<<<dim3(NN * DD / 256), dim3(256), 0, stream>>>(x, W_node, b_node, h, h_bf);
    k_count<<<dim3(EE / 256), dim3(256), 0, stream>>>(ei, counts);
    k_scan<<<dim3(1), dim3(1024), 0, stream>>>(counts, row_ptr);
    k_fill<<<dim3(EE / 256), dim3(256), 0, stream>>>(ei, ea, counts, src_perm, ea_bf);
    k_pack<<<dim3(2 * LL * 32768 / 256), dim3(256), 0, stream>>>(W1, W2, Wp1, Wp2);

    for (int l = 0; l < LL; ++l) {
        (void)hipMemsetAsync(stats, 0, 3072, stream);
        k_agg<<<dim3(NN / 4), dim3(256), 0, stream>>>(
            h_bf, ea_bf, We + (size_t)l * FF * DD, be + (size_t)l * DD,
            eps_gin, l, row_ptr, src_perm, z_bf);
        k_gemmB<<<dim3(NB), dim3(256), 0, stream>>>(
            z_bf, Wp1 + (size_t)l * 32768, t_bf, ps1, pq1);
        k_gemmD<<<dim3(NB), dim3(256), 0, stream>>>(
            t_bf, ps1, pq1, g1 + (size_t)l * 256, beta1 + (size_t)l * 256,
            Wp2 + (size_t)l * 32768, vb, ps2, pq2);
        k_fin<<<dim3(NN * DD / 8 / 256), dim3(256), 0, stream>>>(
            vb, ps2, pq2, g_bn + (size_t)l * 128, beta_bn + (size_t)l * 128,
            h, h_bf, (l < LL - 1) ? 1 : 0);
    }
}